// Round 2
// baseline (6933.702 us; speedup 1.0000x reference)
//
#include <hip/hip_runtime.h>
#include <math.h>

// Problem constants (fixed by reference file)
#define NB   512    // N = batch of user pairs
#define MM   254    // M uav nodes
#define SS   256    // S = M + 2 graph nodes per b
#define HH   128    // H hidden
#define RTOT 1278   // 2N + M rows in `outputs`

__device__ __forceinline__ float sigm(float x)   { return 1.0f / (1.0f + __expf(-x)); }
__device__ __forceinline__ float tanh_f(float x) { return 1.0f - 2.0f / (1.0f + __expf(2.0f * x)); }

// Per node row r: e = pos @ W_embed + b_embed (128),
//   W1eR[r][h] = (e @ att_W1)[h]            (row-major, float4-readable)
//   EWi[r][j]  = (e @ lstm_Wi)[j] + lstm_b  (bias folded, j in [0,512))
__global__ __launch_bounds__(128) void precompute_k(
    const float* __restrict__ outputs, const float* __restrict__ Wemb,
    const float* __restrict__ bemb, const float* __restrict__ Wi,
    const float* __restrict__ W1, const float* __restrict__ lb,
    float* __restrict__ EWi, float* __restrict__ W1eR)
{
  int r = blockIdx.x;
  int t = threadIdx.x;  // 128
  __shared__ float e[HH];
  float px = outputs[2 * r], py = outputs[2 * r + 1];
  e[t] = px * Wemb[t] + py * Wemb[HH + t] + bemb[t];
  __syncthreads();
  float acc = 0.f;
#pragma unroll 8
  for (int h = 0; h < HH; ++h) acc = fmaf(e[h], W1[h * HH + t], acc);
  W1eR[(size_t)r * HH + t] = acc;
#pragma unroll
  for (int c4 = 0; c4 < 4; ++c4) {
    int j = t + c4 * HH;
    float a = 0.f;
#pragma unroll 8
    for (int h = 0; h < HH; ++h) a = fmaf(e[h], Wi[h * 512 + j], a);
    EWi[(size_t)r * 512 + j] = a + lb[j];
  }
}

// Wh[128][512] -> WhT[512][128].  grid 128 (kk), block 512 (j): coalesced reads.
__global__ __launch_bounds__(512) void transpose_wh_k(const float* __restrict__ Wh,
                                                      float* __restrict__ WhT)
{
  int kk = blockIdx.x, j = threadIdx.x;
  WhT[j * HH + kk] = Wh[kk * 512 + j];
}

// W2[128][128] -> W2T[128][128]
__global__ __launch_bounds__(128) void transpose_w2_k(const float* __restrict__ W2,
                                                      float* __restrict__ W2T)
{
  int kk = blockIdx.x, j = threadIdx.x;
  W2T[j * HH + kk] = W2[kk * HH + j];
}

// One block per batch element b. 512 threads (8 waves), 2 blocks/CU.
__global__ __launch_bounds__(512, 4) void decode_k(
    const float* __restrict__ outputs, const float* __restrict__ WhT,
    const float* __restrict__ W2T, const float* __restrict__ av,
    const float* __restrict__ EWi, const float* __restrict__ W1eR,
    float* __restrict__ maxd_out)
{
  int b = blockIdx.x;
  int t = threadIdx.x;  // 512

  __shared__ float posS[2 * RTOT];         // all node positions (10.2 KB)
  __shared__ float hS[HH], cS[HH], qS[HH], vS[HH];
  __shared__ float gS[512];
  __shared__ float wvalS[8];
  __shared__ unsigned wkeyS[8];
  __shared__ int actS[254];
  __shared__ int cntS, curS;

  for (int i = t; i < 2 * RTOT; i += 512) posS[i] = outputs[i];
  if (t < HH) { hS[t] = 0.f; cS[t] = 0.f; vS[t] = av[t]; }
  if (t < 254) actS[t] = t + 1;            // s = 1..254 initially active
  if (t == 0) { cntS = 254; curS = b; }
  __syncthreads();

  float px = 0.f, py = 0.f, md = 0.f;      // live only in thread 0
  if (t == 0) { px = posS[2 * b]; py = posS[2 * b + 1]; }

  for (int k = 0; k < SS; ++k) {
    int cur = curS;
    int cnt = cntS;

    // ---- gates[j=t] = EWi[cur][t] (+lb folded) + sum_kk h[kk]*Wh[kk][t]
    {
      float a = EWi[(size_t)cur * 512 + t];
      const float4* wr = (const float4*)(WhT + (size_t)t * HH);
      const float4* h4 = (const float4*)hS;
#pragma unroll 8
      for (int kk = 0; kk < 32; ++kk) {
        float4 w = wr[kk];
        float4 h = h4[kk];
        a = fmaf(h.x, w.x, a); a = fmaf(h.y, w.y, a);
        a = fmaf(h.z, w.z, a); a = fmaf(h.w, w.w, a);
      }
      gS[t] = a;
    }
    __syncthreads();

    // ---- LSTM cell (order: i, f, g, o)
    if (t < HH) {
      float iv = sigm(gS[t]);
      float fv = sigm(gS[HH + t]);
      float gv = tanh_f(gS[2 * HH + t]);
      float ov = sigm(gS[3 * HH + t]);
      float cn = fv * cS[t] + iv * gv;
      cS[t] = cn;
      hS[t] = ov * tanh_f(cn);
    }
    __syncthreads();

    // ---- q[j=t] = sum_kk h[kk]*W2[kk][t]   (sequential kk, exact order)
    if (t < HH) {
      const float4* wr = (const float4*)(W2T + (size_t)t * HH);
      const float4* h4 = (const float4*)hS;
      float a = 0.f;
#pragma unroll 8
      for (int kk = 0; kk < 32; ++kk) {
        float4 w = wr[kk];
        float4 h = h4[kk];
        a = fmaf(h.x, w.x, a); a = fmaf(h.y, w.y, a);
        a = fmaf(h.z, w.z, a); a = fmaf(h.w, w.w, a);
      }
      qS[t] = a;
    }
    __syncthreads();

    // ---- logits over active nodes only; per-s sum over h is sequential
    int cntEff = cnt + (k > 0 ? 1 : 0);    // node 255 re-enters for k>0
    float val = -INFINITY;
    unsigned key = 0xFFFFFFFFu;
    if (t < cntEff) {
      int s = (t == cnt) ? 255 : actS[t];
      int r = (s == 255) ? (NB + b) : (2 * NB + (s - 1));
      const float4* wr = (const float4*)(W1eR + (size_t)r * HH);
      const float4* q4 = (const float4*)qS;
      const float4* v4 = (const float4*)vS;
      float acc = 0.f;
#pragma unroll 8
      for (int h = 0; h < 32; ++h) {
        float4 w = wr[h];
        float4 q = q4[h];
        float4 v = v4[h];
        acc = fmaf(v.x, tanh_f(w.x + q.x), acc);
        acc = fmaf(v.y, tanh_f(w.y + q.y), acc);
        acc = fmaf(v.z, tanh_f(w.z + q.z), acc);
        acc = fmaf(v.w, tanh_f(w.w + q.w), acc);
      }
      val = acc;
      key = ((unsigned)s << 16) | (unsigned)t;   // tie-break: smaller s wins
    }
    // wave-level argmax (no barrier)
#pragma unroll
    for (int off = 1; off < 64; off <<= 1) {
      float v2 = __shfl_xor(val, off);
      unsigned k2 = __shfl_xor(key, off);
      if (v2 > val || (v2 == val && k2 < key)) { val = v2; key = k2; }
    }
    if ((t & 63) == 0) { wvalS[t >> 6] = val; wkeyS[t >> 6] = key; }
    __syncthreads();

    // ---- final pick + state update (thread 0)
    if (t == 0) {
      float bv = wvalS[0]; unsigned bk = wkeyS[0];
#pragma unroll
      for (int w = 1; w < 8; ++w) {
        float v2 = wvalS[w]; unsigned k2 = wkeyS[w];
        if (v2 > bv || (v2 == bv && k2 < bk)) { bv = v2; bk = k2; }
      }
      int s   = (int)(bk >> 16);
      int pos = (int)(bk & 0xFFFFu);
      int rn  = (s == 255) ? (NB + b) : (2 * NB + (s - 1));
      float nx = posS[2 * rn], ny = posS[2 * rn + 1];
      float dx = nx - px, dy = ny - py;
      float d = sqrtf(dx * dx + dy * dy + 1e-12f);
      if (d > md) md = d;
      px = nx; py = ny;
      curS = rn;
      if (s != 255) { actS[pos] = actS[cnt - 1]; cntS = cnt - 1; }
    }
    __syncthreads();
  }
  if (t == 0) maxd_out[b] = md;
}

__global__ __launch_bounds__(512) void reduce_k(const float* __restrict__ maxd,
                                               float* __restrict__ out)
{
  __shared__ float s[512];
  int t = threadIdx.x;
  s[t] = maxd[t];
  __syncthreads();
  for (int off = 256; off > 0; off >>= 1) {
    if (t < off) s[t] += s[t + off];
    __syncthreads();
  }
  if (t == 0) out[0] = s[0] * (1.0f / 512.0f);
}

extern "C" void kernel_launch(void* const* d_in, const int* in_sizes, int n_in,
                              void* d_out, int out_size, void* d_ws, size_t ws_size,
                              hipStream_t stream) {
  const float* outputs = (const float*)d_in[0];
  const float* Wemb    = (const float*)d_in[1];
  const float* bemb    = (const float*)d_in[2];
  const float* Wi      = (const float*)d_in[3];
  const float* Wh      = (const float*)d_in[4];
  const float* lb      = (const float*)d_in[5];
  const float* W1      = (const float*)d_in[6];
  const float* W2      = (const float*)d_in[7];
  const float* av      = (const float*)d_in[8];
  // d_in[9] = N (known constant 512)

  float* ws   = (float*)d_ws;
  float* EWi  = ws;                           // 1278 * 512
  float* W1eR = EWi  + (size_t)RTOT * 512;    // 1278 * 128
  float* WhT  = W1eR + (size_t)RTOT * HH;     // 512 * 128
  float* W2T  = WhT  + (size_t)512 * HH;      // 128 * 128
  float* maxd = W2T  + (size_t)HH * HH;       // 512

  hipLaunchKernelGGL(transpose_wh_k, dim3(HH), dim3(512), 0, stream, Wh, WhT);
  hipLaunchKernelGGL(transpose_w2_k, dim3(HH), dim3(HH), 0, stream, W2, W2T);
  hipLaunchKernelGGL(precompute_k, dim3(RTOT), dim3(HH), 0, stream,
                     outputs, Wemb, bemb, Wi, W1, lb, EWi, W1eR);
  hipLaunchKernelGGL(decode_k, dim3(NB), dim3(512), 0, stream,
                     outputs, WhT, W2T, av, EWi, W1eR, maxd);
  hipLaunchKernelGGL(reduce_k, dim3(1), dim3(512), 0, stream, maxd, (float*)d_out);
}